// Round 4
// baseline (122.333 us; speedup 1.0000x reference)
//
#include <hip/hip_runtime.h>

#define KTAPS 10
#define SKIP  2
#define TRANS 100
#define PAD   ((KTAPS - 1) * SKIP)   // 18
#define NFEAT 231                    // 1 + 10 + 220
#define NIN   4096
#define NT    (NIN - TRANS)          // 3996
#define NROWS 32                     // 8*4
#define TT    32                     // timesteps per tile
#define NTILES ((NT + TT - 1) / TT)  // 125
#define G     4                      // tiles per block

// Emit monomials for pair-index range [PLO,PHI) of the 55 i<=j pairs, fully
// unrolled: every f-offset / tap index is a compile-time constant. Lex order
// matches itertools.combinations_with_replacement(range(10), 3).
template<int PLO, int PHI, bool LIN>
__device__ __forceinline__ void emit_features(const float* __restrict__ tap,
                                              float* __restrict__ frow) {
    if (LIN) {
        frow[0] = 1.0f;
#pragma unroll
        for (int k = 0; k < KTAPS; ++k) frow[1 + k] = tap[k];
    }
    int p = 0, fb = 1 + KTAPS;
#pragma unroll
    for (int i = 0; i < KTAPS; ++i) {
#pragma unroll
        for (int j = i; j < KTAPS; ++j) {
            if (p >= PLO && p < PHI) {
                const float pij = tap[i] * tap[j];
#pragma unroll
                for (int l = j; l < KTAPS; ++l)
                    frow[fb + (l - j)] = pij * tap[l];
            }
            fb += KTAPS - j;
            ++p;
        }
    }
}

// Compute one 32-timestep tile of features into an LDS buffer laid out
// exactly like the output slab ([t][feat], stride 231; 231%32=7 -> the
// fixed-f, t=lane writes are bank-conflict-free).
__device__ __forceinline__ void compute_tile(const float* __restrict__ xrow,
                                             int t0, float* __restrict__ fbuf) {
    const int tl = threadIdx.x & 31;          // both wave halves duplicate rows
    const int wq = threadIdx.x >> 6;          // wave id (uniform)
    int tg = t0 + tl;
    if (tg >= NT) tg = NT - 1;                // tail clamp; rows never copied out

    // lin_k(t) = X[row, t + 82 + 2k]; max index 4095 -> always in-bounds.
    float tap[KTAPS];
#pragma unroll
    for (int k = 0; k < KTAPS; ++k)
        tap[k] = xrow[tg + (TRANS - PAD) + 2 * k];

    float* frow = fbuf + tl * NFEAT;
    switch (wq) {                             // balanced: 56/55/58/62 writes
        case 0:  emit_features< 0,  6, true >(tap, frow); break;
        case 1:  emit_features< 6, 19, false>(tap, frow); break;
        case 2:  emit_features<19, 31, false>(tap, frow); break;
        default: emit_features<31, 55, false>(tap, frow); break;
    }
}

__global__ __launch_bounds__(256) void nvar_kernel(const float* __restrict__ X,
                                                   float* __restrict__ out) {
    // Double-buffered tile stage: 2 * 32 * 231 * 4 = 59,136 B -> 2 blocks/CU.
    __shared__ float buf[2][TT * NFEAT];

    const int row   = blockIdx.y;
    const int tile0 = blockIdx.x * G;
    const float* xrow = X + (size_t)row * NIN;

    if (tile0 >= NTILES) return;              // (never with grid.x=32, G=4... keep safe)

    compute_tile(xrow, tile0 * TT, buf[0]);

#pragma unroll
    for (int g = 0; g < G; ++g) {
        const int tile = tile0 + g;           // block-uniform
        if (tile >= NTILES) break;
        __syncthreads();                      // tile g's LDS writes visible;
                                              // prior ds_reads on buf[g&1^1] done

        // Issue this tile's stores (fire-and-forget), then overlap the next
        // tile's compute with the HBM drain.
        const int t0 = tile * TT;
        const int tcount = min(TT, NT - t0);          // 32 or 28
        const int total4 = (tcount * NFEAT) >> 2;     // %4 == 0 exactly
        float4* __restrict__ o4 =
            reinterpret_cast<float4*>(out + ((size_t)row * NT + t0) * NFEAT);
        const float4* s4 = reinterpret_cast<const float4*>(buf[g & 1]);
        for (int i = threadIdx.x; i < total4; i += 256)
            o4[i] = s4[i];

        if (g + 1 < G && tile + 1 < NTILES)
            compute_tile(xrow, (tile + 1) * TT, buf[(g + 1) & 1]);
    }
}

extern "C" void kernel_launch(void* const* d_in, const int* in_sizes, int n_in,
                              void* d_out, int out_size, void* d_ws, size_t ws_size,
                              hipStream_t stream) {
    const float* X = (const float*)d_in[0];
    float* out = (float*)d_out;
    dim3 grid((NTILES + G - 1) / G, NROWS);   // 32 x 32 = 1024 blocks
    nvar_kernel<<<grid, 256, 0, stream>>>(X, out);
}